// Round 8
// baseline (377.915 us; speedup 1.0000x reference)
//
#include <hip/hip_runtime.h>
#include <hip/hip_bf16.h>
#include <math.h>

typedef unsigned short u16;
typedef unsigned int u32;

#define Bz 2
#define Sz 2048
#define Dz 2048
#define Hz 16
#define HDz 128
#define Mz 4096

typedef __bf16 bf16x8 __attribute__((ext_vector_type(8)));
typedef float f32x4 __attribute__((ext_vector_type(4)));

__device__ __forceinline__ float bf2f(u16 h) {
    union { u32 u; float f; } x; x.u = ((u32)h) << 16; return x.f;
}
__device__ __forceinline__ u16 f2bf(float f) {
    union { float f; u32 u; } x; x.f = f;
    u32 u = x.u;
    return (u16)((u + 0x7FFFu + ((u >> 16) & 1u)) >> 16);
}
// truncating pack (hot path; P in [0,1], bias cancels via consistent l)
__device__ __forceinline__ u32 pack_bf16_trunc(float lo, float hi) {
    union { float f; u32 u; } a, b; a.f = lo; b.f = hi;
    return (a.u >> 16) | (b.u & 0xFFFF0000u);
}
__device__ __forceinline__ u32 pack_bf16_rn(float lo, float hi) {
    return (u32)f2bf(lo) | ((u32)f2bf(hi) << 16);
}
__device__ __forceinline__ float fexp2(float x) {
#if __has_builtin(__builtin_amdgcn_exp2f)
    return __builtin_amdgcn_exp2f(x);
#else
    return exp2f(x);
#endif
}
// sin/cos of (2*pi*tr), tr in revolutions — hardware v_sin/v_cos after v_fract
__device__ __forceinline__ void sincos_rev(float tr, float* sn, float* cn) {
#if __has_builtin(__builtin_amdgcn_fractf) && __has_builtin(__builtin_amdgcn_sinf) && __has_builtin(__builtin_amdgcn_cosf)
    float fu = __builtin_amdgcn_fractf(tr);
    *sn = __builtin_amdgcn_sinf(fu);
    *cn = __builtin_amdgcn_cosf(fu);
#else
    sincosf(tr * 6.283185307179586f, sn, cn);
#endif
}
// async global->LDS, 16B per lane; lds dest = uniform base + lane*16
__device__ __forceinline__ void gl_lds16(const void* g, void* l) {
    __builtin_amdgcn_global_load_lds(
        (const __attribute__((address_space(1))) void*)g,
        (__attribute__((address_space(3))) void*)l, 16, 0, 0);
}

// ---------------- fp32 -> bf16 convert (x) ---------------------------------
__global__ void cvt_f32_bf16(const float* __restrict__ src, u16* __restrict__ dst) {
    size_t i = (size_t)blockIdx.x * blockDim.x + threadIdx.x;  // one per 8 elems
    float4 a = ((const float4*)src)[2 * i];
    float4 b = ((const float4*)src)[2 * i + 1];
    u16 r[8] = {f2bf(a.x), f2bf(a.y), f2bf(a.z), f2bf(a.w),
                f2bf(b.x), f2bf(b.y), f2bf(b.z), f2bf(b.w)};
    *(uint4*)(dst + 8 * i) = *(const uint4*)r;
}

// ---------------- weight transpose+convert: Wt[n][k] = bf16(W[k][n]) -------
// float4 loads (16B/lane), u32-paired bf16 stores (4B/lane).
__global__ void transpose_w(const float* __restrict__ W0, const float* __restrict__ W1,
                            const float* __restrict__ W2, const float* __restrict__ W3,
                            u16* __restrict__ Wt) {
    __shared__ u16 t[64][65];
    const float* src = (blockIdx.z == 0) ? W0 : (blockIdx.z == 1) ? W1
                     : (blockIdx.z == 2) ? W2 : W3;
    u16* dst = Wt + (size_t)blockIdx.z * (Dz * Dz);
    int x = blockIdx.x * 64, y = blockIdx.y * 64;
    // load: 4 consecutive source cols (float4) x 4 rows per thread
    {
        int c4 = (threadIdx.x & 15) * 4, r0 = (threadIdx.x >> 4) * 4;
#pragma unroll
        for (int i = 0; i < 4; i++) {
            int r = r0 + i;
            float4 v = *(const float4*)&src[(size_t)(y + r) * Dz + x + c4];
            t[r][c4 + 0] = f2bf(v.x); t[r][c4 + 1] = f2bf(v.y);
            t[r][c4 + 2] = f2bf(v.z); t[r][c4 + 3] = f2bf(v.w);
        }
    }
    __syncthreads();
    // store: 2 consecutive dst cols (one u32) x 8 dst rows per thread
    {
        int ce = (threadIdx.x & 31) * 2, r0 = (threadIdx.x >> 5) * 8;
#pragma unroll
        for (int j = 0; j < 8; j++) {
            int r = r0 + j;                            // dst row = source col
            u32 w = (u32)t[ce][r] | ((u32)t[ce + 1][r] << 16);
            *(u32*)&dst[(size_t)(x + r) * Dz + y + ce] = w;
        }
    }
}

// ---------------- GEMM: C = A[M,K](bf16) * Wt[N,K]^T(bf16), 128x128 tile ----
// global_load_lds staging + XOR-swizzled LDS (block cb of row r stored at
// cb ^ (r&7)) -> conflict-free ds_read_b128 fragment reads.
// MODE 0: fp32 row-major store. MODE 1: bf16 scatter (z=0/1 [B,H,S,HD] with
// FUSED RoPE applied to the fp32 accumulator via native v_sin/v_cos;
// z=2 [B,H,HD,S], no RoPE).
// XCD-aware block swizzle (T1): 512-block (x,y) plane, 512 % 8 == 0 ->
// bijective simple form; each XCD owns 64 contiguous work ids = 4 A-panels
// (2 MB, L2-resident). Verified r4: FETCH 198->147 MB, dur neutral
// (structure-bound at ~930 TF, the m97 ceiling).
template <int MODE>
__global__ void gemm_bt(const u16* __restrict__ A, const u16* __restrict__ BtBase,
                        void* __restrict__ CBase) {
    const int z = blockIdx.z;
    const u16* Bt = BtBase + (size_t)z * (Dz * Dz);
    const int tid = threadIdx.x, lane = tid & 63, wave = tid >> 6;
    const int ln = lane & 15, qd = lane >> 4;
    // XCD swizzle over the 512-block (x,y) plane (assumes gridDim = (16,32,z))
    const int lid = blockIdx.y * 16 + blockIdx.x;
    const int wid = (lid & 7) * 64 + (lid >> 3);
    const int m0 = (wid >> 4) * 128, n0 = (wid & 15) * 128;

    __shared__ __align__(16) u16 As[128][64];
    __shared__ __align__(16) u16 Bs[128][64];

    f32x4 acc[4][4];
#pragma unroll
    for (int i = 0; i < 4; i++)
#pragma unroll
        for (int j = 0; j < 4; j++) acc[i][j] = (f32x4){0.f, 0.f, 0.f, 0.f};

    const int wm = (wave >> 1) * 64, wn = (wave & 1) * 64;
    const int lr8 = lane >> 3;                         // row-within-8 (= row&7)
    const int bgo = (((lane & 7) ^ lr8) * 8);          // swizzled u16 col offset
    const int x7 = ln & 7;

    for (int k0 = 0; k0 < Dz; k0 += 64) {
        const u16* ga = A  + (size_t)(m0 + wave * 32 + lr8) * Dz + k0 + bgo;
        const u16* gb = Bt + (size_t)(n0 + wave * 32 + lr8) * Dz + k0 + bgo;
#pragma unroll
        for (int i = 0; i < 4; i++) {
            gl_lds16(ga + (size_t)(8 * i) * Dz, &As[wave * 32 + 8 * i][0]);
            gl_lds16(gb + (size_t)(8 * i) * Dz, &Bs[wave * 32 + 8 * i][0]);
        }
        __syncthreads();
#pragma unroll
        for (int kc = 0; kc < 2; kc++) {
            bf16x8 af[4], bff[4];
            const int cs = ((4 * kc + qd) ^ x7) * 8;   // swizzled fragment col
#pragma unroll
            for (int i = 0; i < 4; i++) {
                af[i]  = *(const bf16x8*)&As[wm + i * 16 + ln][cs];
                bff[i] = *(const bf16x8*)&Bs[wn + i * 16 + ln][cs];
            }
#pragma unroll
            for (int i = 0; i < 4; i++)
#pragma unroll
                for (int j = 0; j < 4; j++)
                    acc[i][j] = __builtin_amdgcn_mfma_f32_16x16x32_bf16(
                        af[i], bff[j], acc[i][j], 0, 0, 0);
        }
        __syncthreads();
    }

#pragma unroll
    for (int i = 0; i < 4; i++) {
#pragma unroll
        for (int j = 0; j < 4; j++) {
#pragma unroll
            for (int r = 0; r < 4; r++) {
                int row = m0 + wm + i * 16 + qd * 4 + r;
                int col = n0 + wn + j * 16 + ln;
                if (MODE == 0) {
                    ((float*)CBase)[(size_t)row * Dz + col] = acc[i][j][r];
                } else {
                    u16* C = (u16*)CBase + (size_t)z * ((size_t)Mz * Dz);
                    float v = acc[i][j][r];
                    int bb = row >> 11, ss = row & 2047;
                    int hh = col >> 7, hd = col & 127;
                    if (z == 2) {
                        C[((size_t)(bb * Hz + hh) * HDz + hd) * Sz + ss] = f2bf(v);
                    } else {
                        // fused RoPE: partner x[hd^1] lives in adjacent lane
                        // (col = ... + ln). rotate_half: even hd -> -x[hd+1],
                        // odd hd -> +x[hd-1]. theta = ss*10000^(-(hd&63)/64);
                        // computed in REVOLUTIONS for native v_sin/v_cos:
                        // fr = 10000^(-d/64)/(2pi) = exp2(-LG*d - log2(2pi)).
                        float partner = __shfl_xor(v, 1);
                        const float LG = 0.20762050593046017f;   // log2(10000)/64
                        const float L2PI = 2.6514961294723187f;  // log2(2*pi)
                        float fr = fexp2(-LG * (float)(hd & 63) - L2PI);
                        float sn, cn;
                        sincos_rev((float)ss * fr, &sn, &cn);
                        float rot = (hd & 1) ? partner : -partner;
                        float y = v * cn + rot * sn;
                        // 1/sqrt(HD)*log2(e) folded into Q (exp2-domain flash)
                        if (z == 0) y *= 0.12751771218027603f;
                        C[((size_t)(bb * Hz + hh) * Sz + ss) * HDz + hd] = f2bf(y);
                    }
                }
            }
        }
    }
}

// ---------------- causal flash attention, S^T formulation ------------------
// Q,K: [B,H,S,HD] (Q pre-scaled, RoPE fused upstream); Vt: [B,H,HD,S];
// O: [B,S,H*HD]. Block: 8 waves x 16 q-cols = 128 q; k-tiles of 64 keys.
// (r7->r8: q-tile 64->128 halves K/V staging tiles per (b,h) 528->272 and
// barrier count likewise; per-wave state unchanged. Lower 4 waves burn one
// fully-masked tile per block, +3% MFMA.)
// S^T = K*Q^T; O^T = V^T*P^T; l via ones-row of V. XOR-swizzled Ks/Vs.
// Load-balance: 512 blocks -> 2/CU pairing {bid, bid+256} = {g, g+8};
// qb = g<8 ? g : 23-g makes per-CU tile-sum constant (34). bh = bid&31
// unchanged -> per-XCD K/V L2 locality preserved.
__global__ __launch_bounds__(512, 4)
void flash_attn(const u16* __restrict__ Q, const u16* __restrict__ Kk,
                const u16* __restrict__ Vt, u16* __restrict__ O) {
    const int tid = threadIdx.x, lane = tid & 63, wave = tid >> 6;  // 0..7
    const int ln = lane & 15, qd = lane >> 4;
    const int bh = blockIdx.x & 31;
    const int g = blockIdx.x >> 5;                     // 0..15
    const int qb = (g < 8) ? g : 23 - g;               // q-block, bijective
    const int b = bh >> 4, h = bh & 15;
    const int q0 = qb * 128;
    const u16* Qh = Q  + (size_t)bh * Sz * HDz;
    const u16* Kh = Kk + (size_t)bh * Sz * HDz;
    const u16* Vh = Vt + (size_t)bh * HDz * Sz;

    __shared__ __align__(16) u16 Ks[64][128];          // [key][d], swizzled blocks
    __shared__ __align__(16) u16 Vs[144][64];          // [d][key], swizzled; rows 128..143 ones-block

    // init ones-row block of Vs (row-uniform -> swizzle-invariant)
    for (int idx = tid; idx < 16 * 64; idx += 512) {
        int rr = idx >> 6, cc = idx & 63;
        Vs[128 + rr][cc] = (rr == 0) ? (u16)0x3F80 : (u16)0;
    }

    // Q B-fragments, direct from global (q = ln column, k = qd*8 + j)
    const int qabs = q0 + wave * 16 + ln;
    bf16x8 qf[4];
#pragma unroll
    for (int kc = 0; kc < 4; kc++) {
        uint4 t = *(const uint4*)(Qh + (size_t)qabs * HDz + kc * 32 + qd * 8);
        qf[kc] = *(const bf16x8*)&t;
    }

    float m_run = -INFINITY;
    f32x4 oa[9];                                       // O^T[d][q=ln]; oa[8] = l row
#pragma unroll
    for (int n = 0; n < 9; n++) oa[n] = (f32x4){0.f, 0.f, 0.f, 0.f};

    const int x7 = ln & 7;
    const int l4 = lane >> 4, c16 = lane & 15;         // K staging map
    const int lr8 = lane >> 3;                         // V staging map
    const int bgv = ((lane & 7) ^ lr8) * 8;

    const int kmax = q0 + 64;                          // covers q up to q0+127
    for (int k0 = 0; k0 <= kmax; k0 += 64) {
        // async stage K (64x128) and V (128x64), swizzled; 8 waves: 2+2 issues
        {
#pragma unroll
            for (int i = 0; i < 2; i++) {
                int rw = 4 * i + l4;                   // (row & 7)
                const u16* gk = Kh + (size_t)(k0 + 8 * wave + 4 * i + l4) * HDz
                                   + ((c16 ^ rw) * 8);
                gl_lds16(gk, &Ks[8 * wave + 4 * i][0]);
            }
            const u16* gv = Vh + (size_t)(16 * wave + lr8) * Sz + k0 + bgv;
#pragma unroll
            for (int i = 0; i < 2; i++)
                gl_lds16(gv + (size_t)(8 * i) * Sz, &Vs[16 * wave + 8 * i][0]);
        }
        __syncthreads();

        // S^T tile: C[key=mt*16+qd*4+r][q=ln]
        f32x4 sc4[4];
#pragma unroll
        for (int mt = 0; mt < 4; mt++) sc4[mt] = (f32x4){0.f, 0.f, 0.f, 0.f};
#pragma unroll
        for (int kc = 0; kc < 4; kc++) {
            const int cs = ((4 * kc + qd) ^ x7) * 8;
#pragma unroll
            for (int mt = 0; mt < 4; mt++) {
                bf16x8 kf = *(const bf16x8*)&Ks[mt * 16 + ln][cs];
                sc4[mt] = __builtin_amdgcn_mfma_f32_16x16x32_bf16(kf, qf[kc], sc4[mt], 0, 0, 0);
            }
        }
        if (k0 >= q0) {                                // diag + super-diag tiles
#pragma unroll
            for (int mt = 0; mt < 4; mt++)
#pragma unroll
                for (int r = 0; r < 4; r++)
                    if (k0 + mt * 16 + qd * 4 + r > qabs) sc4[mt][r] = -3e38f;
        }

        // row max: in-register + cross-quad
        float rm = -3e38f;
#pragma unroll
        for (int mt = 0; mt < 4; mt++) {
            rm = fmaxf(rm, fmaxf(fmaxf(sc4[mt][0], sc4[mt][1]),
                                 fmaxf(sc4[mt][2], sc4[mt][3])));
        }
        rm = fmaxf(rm, __shfl_xor(rm, 16));
        rm = fmaxf(rm, __shfl_xor(rm, 32));
        float mn = fmaxf(m_run, rm);
        bool resc = (__ballot(mn > m_run) != 0ULL);
        float al = fexp2(m_run - mn);
        m_run = mn;
        if (resc) {
#pragma unroll
            for (int n = 0; n < 9; n++)
#pragma unroll
                for (int r = 0; r < 4; r++) oa[n][r] *= al;
        }

        // P = exp2(S - m), packed bf16 pairs: pku[mt*2+t] = keys(mt*16+qd*4+2t, +1)
        u32 pku[8];
#pragma unroll
        for (int mt = 0; mt < 4; mt++) {
#pragma unroll
            for (int t = 0; t < 2; t++)
                pku[mt * 2 + t] = pack_bf16_trunc(fexp2(sc4[mt][2 * t] - mn),
                                                  fexp2(sc4[mt][2 * t + 1] - mn));
        }

        // O^T += V^T * P^T  (B-frag of P^T built by register shuffle)
#pragma unroll
        for (int kc = 0; kc < 2; kc++) {
            union { u32 w[4]; bf16x8 v; } pb;
#pragma unroll
            for (int s = 0; s < 4; s++) {
                int srcl = ((2 * (qd & 1) + (s >> 1)) << 4) | ln;
                u32 a0 = (u32)__shfl((int)pku[4 * kc + (s & 1)], srcl);
                u32 a1 = (u32)__shfl((int)pku[4 * kc + 2 + (s & 1)], srcl);
                pb.w[s] = (qd & 2) ? a1 : a0;
            }
            const int cs = ((4 * kc + qd) ^ x7) * 8;
#pragma unroll
            for (int mt = 0; mt < 9; mt++) {
                bf16x8 vf = *(const bf16x8*)&Vs[mt * 16 + ln][cs];
                oa[mt] = __builtin_amdgcn_mfma_f32_16x16x32_bf16(vf, pb.v, oa[mt], 0, 0, 0);
            }
        }
        __syncthreads();
    }

    // l lives in quad 0, reg 0 of oa[8]; broadcast, normalize, store O[q][d]
    float l = __shfl(oa[8][0], ln);
    float linv = 1.0f / l;
    u16* op = O + ((size_t)b * Sz + qabs) * Dz + h * HDz;
#pragma unroll
    for (int mt = 0; mt < 8; mt++) {
        u32 w0 = pack_bf16_rn(oa[mt][0] * linv, oa[mt][1] * linv);
        u32 w1 = pack_bf16_rn(oa[mt][2] * linv, oa[mt][3] * linv);
        uint2 ww; ww.x = w0; ww.y = w1;
        *(uint2*)(op + mt * 16 + qd * 4) = ww;
    }
}

// ---------------------------------------------------------------------------
extern "C" void kernel_launch(void* const* d_in, const int* in_sizes, int n_in,
                              void* d_out, int out_size, void* d_ws, size_t ws_size,
                              hipStream_t stream) {
    const float* x  = (const float*)d_in[0];
    const float* Wq = (const float*)d_in[1];
    const float* Wk = (const float*)d_in[2];
    const float* Wv = (const float*)d_in[3];
    const float* Wo = (const float*)d_in[4];
    u16* ws  = (u16*)d_ws;

    u16* wt = ws;                       // 4 * 4,194,304 transposed bf16 weights (32 MB)
    u16* q  = ws + 16777216;            // [B,H,S,HD] (RoPE+scale fused in gemm)
    u16* kk = q + 8388608;              // [B,H,S,HD] (RoPE fused in gemm)
    u16* v  = kk + 8388608;             // [B,H,HD,S]
    u16* xb = v + 8388608;              // bf16(x); reused as o after gemm<1>
    u16* o  = xb;

    cvt_f32_bf16<<<dim3(4096), 256, 0, stream>>>(x, xb);
    transpose_w<<<dim3(32, 32, 4), 256, 0, stream>>>(Wq, Wk, Wv, Wo, wt);
    gemm_bt<1><<<dim3(16, 32, 3), 256, 0, stream>>>(xb, wt, q);
    flash_attn<<<dim3(512), 512, 0, stream>>>(q, kk, v, o);
    gemm_bt<0><<<dim3(16, 32, 1), 256, 0, stream>>>(o, wt + 3 * 4194304, (float*)d_out);
}

// Round 9
// 363.175 us; speedup vs baseline: 1.0406x; 1.0406x over previous
//
#include <hip/hip_runtime.h>
#include <hip/hip_bf16.h>
#include <math.h>

typedef unsigned short u16;
typedef unsigned int u32;

#define Bz 2
#define Sz 2048
#define Dz 2048
#define Hz 16
#define HDz 128
#define Mz 4096

typedef __bf16 bf16x8 __attribute__((ext_vector_type(8)));
typedef float f32x4 __attribute__((ext_vector_type(4)));

__device__ __forceinline__ float bf2f(u16 h) {
    union { u32 u; float f; } x; x.u = ((u32)h) << 16; return x.f;
}
__device__ __forceinline__ u16 f2bf(float f) {
    union { float f; u32 u; } x; x.f = f;
    u32 u = x.u;
    return (u16)((u + 0x7FFFu + ((u >> 16) & 1u)) >> 16);
}
// truncating pack (hot path; P in [0,1], bias cancels via consistent l)
__device__ __forceinline__ u32 pack_bf16_trunc(float lo, float hi) {
    union { float f; u32 u; } a, b; a.f = lo; b.f = hi;
    return (a.u >> 16) | (b.u & 0xFFFF0000u);
}
__device__ __forceinline__ u32 pack_bf16_rn(float lo, float hi) {
    return (u32)f2bf(lo) | ((u32)f2bf(hi) << 16);
}
__device__ __forceinline__ float fexp2(float x) {
#if __has_builtin(__builtin_amdgcn_exp2f)
    return __builtin_amdgcn_exp2f(x);
#else
    return exp2f(x);
#endif
}
// sin/cos of (2*pi*tr), tr in revolutions — hardware v_sin/v_cos after v_fract
__device__ __forceinline__ void sincos_rev(float tr, float* sn, float* cn) {
#if __has_builtin(__builtin_amdgcn_fractf) && __has_builtin(__builtin_amdgcn_sinf) && __has_builtin(__builtin_amdgcn_cosf)
    float fu = __builtin_amdgcn_fractf(tr);
    *sn = __builtin_amdgcn_sinf(fu);
    *cn = __builtin_amdgcn_cosf(fu);
#else
    sincosf(tr * 6.283185307179586f, sn, cn);
#endif
}
// async global->LDS, 16B per lane; lds dest = uniform base + lane*16
__device__ __forceinline__ void gl_lds16(const void* g, void* l) {
    __builtin_amdgcn_global_load_lds(
        (const __attribute__((address_space(1))) void*)g,
        (__attribute__((address_space(3))) void*)l, 16, 0, 0);
}

// ---------------- fused prep: weight transpose+convert AND x fp32->bf16 ----
// z<4: Wt[z][n][k] = bf16(W_z[k][n]) (64x64 LDS tile; float4 loads, u32
// paired stores). z>=4: bf16 convert of x quarter (z-4), 8 elems/thread.
// One dispatch instead of two -> one launch gap saved; cvt blocks fill CUs
// while transpose blocks sit at their LDS barrier.
__global__ void prep(const float* __restrict__ x, const float* __restrict__ W0,
                     const float* __restrict__ W1, const float* __restrict__ W2,
                     const float* __restrict__ W3, u16* __restrict__ Wt,
                     u16* __restrict__ xb) {
    const int z = blockIdx.z;
    if (z >= 4) {
        // cvt: 1024 blocks per quarter x 256 threads x 8 elems
        size_t bid = (size_t)(blockIdx.y * 32 + blockIdx.x) + (size_t)(z - 4) * 1024;
        size_t i = bid * 256 + threadIdx.x;            // one per 8 elems
        float4 a = ((const float4*)x)[2 * i];
        float4 b = ((const float4*)x)[2 * i + 1];
        u16 r[8] = {f2bf(a.x), f2bf(a.y), f2bf(a.z), f2bf(a.w),
                    f2bf(b.x), f2bf(b.y), f2bf(b.z), f2bf(b.w)};
        *(uint4*)(xb + 8 * i) = *(const uint4*)r;
        return;
    }
    __shared__ u16 t[64][65];
    const float* src = (z == 0) ? W0 : (z == 1) ? W1 : (z == 2) ? W2 : W3;
    u16* dst = Wt + (size_t)z * (Dz * Dz);
    int x0 = blockIdx.x * 64, y0 = blockIdx.y * 64;
    // load: 4 consecutive source cols (float4) x 4 rows per thread
    {
        int c4 = (threadIdx.x & 15) * 4, r0 = (threadIdx.x >> 4) * 4;
#pragma unroll
        for (int i = 0; i < 4; i++) {
            int r = r0 + i;
            float4 v = *(const float4*)&src[(size_t)(y0 + r) * Dz + x0 + c4];
            t[r][c4 + 0] = f2bf(v.x); t[r][c4 + 1] = f2bf(v.y);
            t[r][c4 + 2] = f2bf(v.z); t[r][c4 + 3] = f2bf(v.w);
        }
    }
    __syncthreads();
    // store: 2 consecutive dst cols (one u32) x 8 dst rows per thread
    {
        int ce = (threadIdx.x & 31) * 2, r0 = (threadIdx.x >> 5) * 8;
#pragma unroll
        for (int j = 0; j < 8; j++) {
            int r = r0 + j;                            // dst row = source col
            u32 w = (u32)t[ce][r] | ((u32)t[ce + 1][r] << 16);
            *(u32*)&dst[(size_t)(x0 + r) * Dz + y0 + ce] = w;
        }
    }
}

// ---------------- GEMM: C = A[M,K](bf16) * Wt[N,K]^T(bf16), 128x128 tile ----
// global_load_lds staging + XOR-swizzled LDS (block cb of row r stored at
// cb ^ (r&7)) -> conflict-free ds_read_b128 fragment reads.
// MODE 0: fp32 row-major store. MODE 1: bf16 scatter (z=0/1 [B,H,S,HD] with
// FUSED RoPE applied to the fp32 accumulator via native v_sin/v_cos;
// z=2 [B,H,HD,S], no RoPE).
// XCD-aware block swizzle (T1): 512-block (x,y) plane, 512 % 8 == 0 ->
// bijective simple form; each XCD owns 64 contiguous work ids = 4 A-panels
// (2 MB, L2-resident). Verified r4: FETCH 198->147 MB, dur neutral
// (structure-bound at ~930 TF, the m97 ceiling).
template <int MODE>
__global__ void gemm_bt(const u16* __restrict__ A, const u16* __restrict__ BtBase,
                        void* __restrict__ CBase) {
    const int z = blockIdx.z;
    const u16* Bt = BtBase + (size_t)z * (Dz * Dz);
    const int tid = threadIdx.x, lane = tid & 63, wave = tid >> 6;
    const int ln = lane & 15, qd = lane >> 4;
    // XCD swizzle over the 512-block (x,y) plane (assumes gridDim = (16,32,z))
    const int lid = blockIdx.y * 16 + blockIdx.x;
    const int wid = (lid & 7) * 64 + (lid >> 3);
    const int m0 = (wid >> 4) * 128, n0 = (wid & 15) * 128;

    __shared__ __align__(16) u16 As[128][64];
    __shared__ __align__(16) u16 Bs[128][64];

    f32x4 acc[4][4];
#pragma unroll
    for (int i = 0; i < 4; i++)
#pragma unroll
        for (int j = 0; j < 4; j++) acc[i][j] = (f32x4){0.f, 0.f, 0.f, 0.f};

    const int wm = (wave >> 1) * 64, wn = (wave & 1) * 64;
    const int lr8 = lane >> 3;                         // row-within-8 (= row&7)
    const int bgo = (((lane & 7) ^ lr8) * 8);          // swizzled u16 col offset
    const int x7 = ln & 7;

    for (int k0 = 0; k0 < Dz; k0 += 64) {
        const u16* ga = A  + (size_t)(m0 + wave * 32 + lr8) * Dz + k0 + bgo;
        const u16* gb = Bt + (size_t)(n0 + wave * 32 + lr8) * Dz + k0 + bgo;
#pragma unroll
        for (int i = 0; i < 4; i++) {
            gl_lds16(ga + (size_t)(8 * i) * Dz, &As[wave * 32 + 8 * i][0]);
            gl_lds16(gb + (size_t)(8 * i) * Dz, &Bs[wave * 32 + 8 * i][0]);
        }
        __syncthreads();
#pragma unroll
        for (int kc = 0; kc < 2; kc++) {
            bf16x8 af[4], bff[4];
            const int cs = ((4 * kc + qd) ^ x7) * 8;   // swizzled fragment col
#pragma unroll
            for (int i = 0; i < 4; i++) {
                af[i]  = *(const bf16x8*)&As[wm + i * 16 + ln][cs];
                bff[i] = *(const bf16x8*)&Bs[wn + i * 16 + ln][cs];
            }
#pragma unroll
            for (int i = 0; i < 4; i++)
#pragma unroll
                for (int j = 0; j < 4; j++)
                    acc[i][j] = __builtin_amdgcn_mfma_f32_16x16x32_bf16(
                        af[i], bff[j], acc[i][j], 0, 0, 0);
        }
        __syncthreads();
    }

#pragma unroll
    for (int i = 0; i < 4; i++) {
#pragma unroll
        for (int j = 0; j < 4; j++) {
#pragma unroll
            for (int r = 0; r < 4; r++) {
                int row = m0 + wm + i * 16 + qd * 4 + r;
                int col = n0 + wn + j * 16 + ln;
                if (MODE == 0) {
                    ((float*)CBase)[(size_t)row * Dz + col] = acc[i][j][r];
                } else {
                    u16* C = (u16*)CBase + (size_t)z * ((size_t)Mz * Dz);
                    float v = acc[i][j][r];
                    int bb = row >> 11, ss = row & 2047;
                    int hh = col >> 7, hd = col & 127;
                    if (z == 2) {
                        C[((size_t)(bb * Hz + hh) * HDz + hd) * Sz + ss] = f2bf(v);
                    } else {
                        // fused RoPE: partner x[hd^1] lives in adjacent lane
                        // (col = ... + ln). rotate_half: even hd -> -x[hd+1],
                        // odd hd -> +x[hd-1]. theta = ss*10000^(-(hd&63)/64);
                        // computed in REVOLUTIONS for native v_sin/v_cos:
                        // fr = 10000^(-d/64)/(2pi) = exp2(-LG*d - log2(2pi)).
                        float partner = __shfl_xor(v, 1);
                        const float LG = 0.20762050593046017f;   // log2(10000)/64
                        const float L2PI = 2.6514961294723187f;  // log2(2*pi)
                        float fr = fexp2(-LG * (float)(hd & 63) - L2PI);
                        float sn, cn;
                        sincos_rev((float)ss * fr, &sn, &cn);
                        float rot = (hd & 1) ? partner : -partner;
                        float y = v * cn + rot * sn;
                        // 1/sqrt(HD)*log2(e) folded into Q (exp2-domain flash)
                        if (z == 0) y *= 0.12751771218027603f;
                        C[((size_t)(bb * Hz + hh) * Sz + ss) * HDz + hd] = f2bf(y);
                    }
                }
            }
        }
    }
}

// ---------------- causal flash attention, S^T formulation ------------------
// Q,K: [B,H,S,HD] (Q pre-scaled, RoPE fused upstream); Vt: [B,H,HD,S];
// O: [B,S,H*HD]. Block: 4 waves x 16 q-cols = 64 q; k-tiles of 64 keys.
// (r8's 128-q variant regressed ~7us: 2 blocks/CU lost the inter-block TLP
// that hides single-buffered staging; reverted to 64-q / 4 blocks/CU.)
// S^T = K*Q^T; O^T = V^T*P^T; l via ones-row of V. XOR-swizzled Ks/Vs.
// Load-balanced qt map: co-resident blocks {bid, bid+256, +512, +768} get
// qt = {m, 31-m, 8+m, 23-m} (bijective over 0..31): per-CU key-sum constant
// 66 tiles. bh = bid&31 -> per-XCD K/V L2 locality preserved.
__global__ __launch_bounds__(256, 4)
void flash_attn(const u16* __restrict__ Q, const u16* __restrict__ Kk,
                const u16* __restrict__ Vt, u16* __restrict__ O) {
    const int tid = threadIdx.x, lane = tid & 63, wave = tid >> 6;
    const int ln = lane & 15, qd = lane >> 4;
    const int bh = blockIdx.x & 31;
    const int g = blockIdx.x >> 5;                     // 0..31
    const int gm = g & 7, gj = g >> 3;
    const int qt = (gj == 0) ? gm : (gj == 1) ? 31 - gm
                 : (gj == 2) ? 8 + gm : 23 - gm;
    const int b = bh >> 4, h = bh & 15;
    const int q0 = qt * 64;
    const u16* Qh = Q  + (size_t)bh * Sz * HDz;
    const u16* Kh = Kk + (size_t)bh * Sz * HDz;
    const u16* Vh = Vt + (size_t)bh * HDz * Sz;

    __shared__ __align__(16) u16 Ks[64][128];          // [key][d], swizzled blocks
    __shared__ __align__(16) u16 Vs[144][64];          // [d][key], swizzled; rows 128..143 ones-block

    // init ones-row block of Vs (row-uniform -> swizzle-invariant)
    for (int idx = tid; idx < 16 * 64; idx += 256) {
        int rr = idx >> 6, cc = idx & 63;
        Vs[128 + rr][cc] = (rr == 0) ? (u16)0x3F80 : (u16)0;
    }

    // Q B-fragments, direct from global (q = ln column, k = qd*8 + j)
    const int qabs = q0 + wave * 16 + ln;
    bf16x8 qf[4];
#pragma unroll
    for (int kc = 0; kc < 4; kc++) {
        uint4 t = *(const uint4*)(Qh + (size_t)qabs * HDz + kc * 32 + qd * 8);
        qf[kc] = *(const bf16x8*)&t;
    }

    float m_run = -INFINITY;
    f32x4 oa[9];                                       // O^T[d][q=ln]; oa[8] = l row
#pragma unroll
    for (int n = 0; n < 9; n++) oa[n] = (f32x4){0.f, 0.f, 0.f, 0.f};

    const int x7 = ln & 7;
    const int l4 = lane >> 4, c16 = lane & 15;         // K staging map
    const int lr8 = lane >> 3;                         // V staging map
    const int bgv = ((lane & 7) ^ lr8) * 8;

    for (int k0 = 0; k0 <= q0; k0 += 64) {
        // async stage K (64x128) and V (128x64), swizzled
        {
#pragma unroll
            for (int i = 0; i < 4; i++) {
                int rw = 4 * (i & 1) + l4;             // (row & 7)
                const u16* gk = Kh + (size_t)(k0 + 16 * wave + 4 * i + l4) * HDz
                                   + ((c16 ^ rw) * 8);
                gl_lds16(gk, &Ks[16 * wave + 4 * i][0]);
            }
            const u16* gv = Vh + (size_t)(32 * wave + lr8) * Sz + k0 + bgv;
#pragma unroll
            for (int i = 0; i < 4; i++)
                gl_lds16(gv + (size_t)(8 * i) * Sz, &Vs[32 * wave + 8 * i][0]);
        }
        __syncthreads();

        // S^T tile: C[key=mt*16+qd*4+r][q=ln]
        f32x4 sc4[4];
#pragma unroll
        for (int mt = 0; mt < 4; mt++) sc4[mt] = (f32x4){0.f, 0.f, 0.f, 0.f};
#pragma unroll
        for (int kc = 0; kc < 4; kc++) {
            const int cs = ((4 * kc + qd) ^ x7) * 8;
#pragma unroll
            for (int mt = 0; mt < 4; mt++) {
                bf16x8 kf = *(const bf16x8*)&Ks[mt * 16 + ln][cs];
                sc4[mt] = __builtin_amdgcn_mfma_f32_16x16x32_bf16(kf, qf[kc], sc4[mt], 0, 0, 0);
            }
        }
        if (k0 == q0) {                                // causal mask, diagonal tile only
#pragma unroll
            for (int mt = 0; mt < 4; mt++)
#pragma unroll
                for (int r = 0; r < 4; r++)
                    if (mt * 16 + qd * 4 + r > 16 * wave + ln) sc4[mt][r] = -3e38f;
        }

        // row max: in-register + cross-quad
        float rm = -3e38f;
#pragma unroll
        for (int mt = 0; mt < 4; mt++) {
            rm = fmaxf(rm, fmaxf(fmaxf(sc4[mt][0], sc4[mt][1]),
                                 fmaxf(sc4[mt][2], sc4[mt][3])));
        }
        rm = fmaxf(rm, __shfl_xor(rm, 16));
        rm = fmaxf(rm, __shfl_xor(rm, 32));
        float mn = fmaxf(m_run, rm);
        bool resc = (__ballot(mn > m_run) != 0ULL);
        float al = fexp2(m_run - mn);
        m_run = mn;
        if (resc) {
#pragma unroll
            for (int n = 0; n < 9; n++)
#pragma unroll
                for (int r = 0; r < 4; r++) oa[n][r] *= al;
        }

        // P = exp2(S - m), packed bf16 pairs: pku[mt*2+t] = keys(mt*16+qd*4+2t, +1)
        u32 pku[8];
#pragma unroll
        for (int mt = 0; mt < 4; mt++) {
#pragma unroll
            for (int t = 0; t < 2; t++)
                pku[mt * 2 + t] = pack_bf16_trunc(fexp2(sc4[mt][2 * t] - mn),
                                                  fexp2(sc4[mt][2 * t + 1] - mn));
        }

        // O^T += V^T * P^T  (B-frag of P^T built by register shuffle)
#pragma unroll
        for (int kc = 0; kc < 2; kc++) {
            union { u32 w[4]; bf16x8 v; } pb;
#pragma unroll
            for (int s = 0; s < 4; s++) {
                int srcl = ((2 * (qd & 1) + (s >> 1)) << 4) | ln;
                u32 a0 = (u32)__shfl((int)pku[4 * kc + (s & 1)], srcl);
                u32 a1 = (u32)__shfl((int)pku[4 * kc + 2 + (s & 1)], srcl);
                pb.w[s] = (qd & 2) ? a1 : a0;
            }
            const int cs = ((4 * kc + qd) ^ x7) * 8;
#pragma unroll
            for (int mt = 0; mt < 9; mt++) {
                bf16x8 vf = *(const bf16x8*)&Vs[mt * 16 + ln][cs];
                oa[mt] = __builtin_amdgcn_mfma_f32_16x16x32_bf16(vf, pb.v, oa[mt], 0, 0, 0);
            }
        }
        __syncthreads();
    }

    // l lives in quad 0, reg 0 of oa[8]; broadcast, normalize, store O[q][d]
    float l = __shfl(oa[8][0], ln);
    float linv = 1.0f / l;
    u16* op = O + ((size_t)b * Sz + qabs) * Dz + h * HDz;
#pragma unroll
    for (int mt = 0; mt < 8; mt++) {
        u32 w0 = pack_bf16_rn(oa[mt][0] * linv, oa[mt][1] * linv);
        u32 w1 = pack_bf16_rn(oa[mt][2] * linv, oa[mt][3] * linv);
        uint2 ww; ww.x = w0; ww.y = w1;
        *(uint2*)(op + mt * 16 + qd * 4) = ww;
    }
}

// ---------------------------------------------------------------------------
extern "C" void kernel_launch(void* const* d_in, const int* in_sizes, int n_in,
                              void* d_out, int out_size, void* d_ws, size_t ws_size,
                              hipStream_t stream) {
    const float* x  = (const float*)d_in[0];
    const float* Wq = (const float*)d_in[1];
    const float* Wk = (const float*)d_in[2];
    const float* Wv = (const float*)d_in[3];
    const float* Wo = (const float*)d_in[4];
    u16* ws  = (u16*)d_ws;

    u16* wt = ws;                       // 4 * 4,194,304 transposed bf16 weights (32 MB)
    u16* q  = ws + 16777216;            // [B,H,S,HD] (RoPE+scale fused in gemm)
    u16* kk = q + 8388608;              // [B,H,S,HD] (RoPE fused in gemm)
    u16* v  = kk + 8388608;             // [B,H,HD,S]
    u16* xb = v + 8388608;              // bf16(x); reused as o after gemm<1>
    u16* o  = xb;

    prep<<<dim3(32, 32, 8), 256, 0, stream>>>(x, Wq, Wk, Wv, Wo, wt, xb);
    gemm_bt<1><<<dim3(16, 32, 3), 256, 0, stream>>>(xb, wt, q);
    flash_attn<<<dim3(1024), 256, 0, stream>>>(q, kk, v, o);
    gemm_bt<0><<<dim3(16, 32, 1), 256, 0, stream>>>(o, wt + 3 * 4194304, (float*)d_out);
}

// Round 10
// 339.980 us; speedup vs baseline: 1.1116x; 1.0682x over previous
//
#include <hip/hip_runtime.h>
#include <hip/hip_bf16.h>
#include <math.h>

typedef unsigned short u16;
typedef unsigned int u32;

#define Bz 2
#define Sz 2048
#define Dz 2048
#define Hz 16
#define HDz 128
#define Mz 4096

typedef __bf16 bf16x8 __attribute__((ext_vector_type(8)));
typedef float f32x4 __attribute__((ext_vector_type(4)));

__device__ __forceinline__ float bf2f(u16 h) {
    union { u32 u; float f; } x; x.u = ((u32)h) << 16; return x.f;
}
__device__ __forceinline__ u16 f2bf(float f) {
    union { float f; u32 u; } x; x.f = f;
    u32 u = x.u;
    return (u16)((u + 0x7FFFu + ((u >> 16) & 1u)) >> 16);
}
// truncating pack (hot path; bias cancels via l summed from SAME truncated values)
__device__ __forceinline__ u32 pack_bf16_trunc(float lo, float hi) {
    union { float f; u32 u; } a, b; a.f = lo; b.f = hi;
    return (a.u >> 16) | (b.u & 0xFFFF0000u);
}
__device__ __forceinline__ u32 pack_bf16_rn(float lo, float hi) {
    return (u32)f2bf(lo) | ((u32)f2bf(hi) << 16);
}
__device__ __forceinline__ float fexp2(float x) {
#if __has_builtin(__builtin_amdgcn_exp2f)
    return __builtin_amdgcn_exp2f(x);
#else
    return exp2f(x);
#endif
}
// sin/cos of (2*pi*tr), tr in revolutions — hardware v_sin/v_cos after v_fract
__device__ __forceinline__ void sincos_rev(float tr, float* sn, float* cn) {
#if __has_builtin(__builtin_amdgcn_fractf) && __has_builtin(__builtin_amdgcn_sinf) && __has_builtin(__builtin_amdgcn_cosf)
    float fu = __builtin_amdgcn_fractf(tr);
    *sn = __builtin_amdgcn_sinf(fu);
    *cn = __builtin_amdgcn_cosf(fu);
#else
    sincosf(tr * 6.283185307179586f, sn, cn);
#endif
}
// async global->LDS, 16B per lane; lds dest = uniform base + lane*16
__device__ __forceinline__ void gl_lds16(const void* g, void* l) {
    __builtin_amdgcn_global_load_lds(
        (const __attribute__((address_space(1))) void*)g,
        (__attribute__((address_space(3))) void*)l, 16, 0, 0);
}

// ---------------- fused prep: weight transpose+convert AND x fp32->bf16 ----
// z<4: Wt[z][n][k] = bf16(W_z[k][n]) (64x64 LDS tile; float4 loads, u32
// paired stores). z>=4: bf16 convert of x quarter (z-4), 8 elems/thread.
// One dispatch instead of two -> one launch gap saved; cvt blocks fill CUs
// while transpose blocks sit at their LDS barrier.
__global__ void prep(const float* __restrict__ x, const float* __restrict__ W0,
                     const float* __restrict__ W1, const float* __restrict__ W2,
                     const float* __restrict__ W3, u16* __restrict__ Wt,
                     u16* __restrict__ xb) {
    const int z = blockIdx.z;
    if (z >= 4) {
        // cvt: 1024 blocks per quarter x 256 threads x 8 elems
        size_t bid = (size_t)(blockIdx.y * 32 + blockIdx.x) + (size_t)(z - 4) * 1024;
        size_t i = bid * 256 + threadIdx.x;            // one per 8 elems
        float4 a = ((const float4*)x)[2 * i];
        float4 b = ((const float4*)x)[2 * i + 1];
        u16 r[8] = {f2bf(a.x), f2bf(a.y), f2bf(a.z), f2bf(a.w),
                    f2bf(b.x), f2bf(b.y), f2bf(b.z), f2bf(b.w)};
        *(uint4*)(xb + 8 * i) = *(const uint4*)r;
        return;
    }
    __shared__ u16 t[64][65];
    const float* src = (z == 0) ? W0 : (z == 1) ? W1 : (z == 2) ? W2 : W3;
    u16* dst = Wt + (size_t)z * (Dz * Dz);
    int x0 = blockIdx.x * 64, y0 = blockIdx.y * 64;
    // load: 4 consecutive source cols (float4) x 4 rows per thread
    {
        int c4 = (threadIdx.x & 15) * 4, r0 = (threadIdx.x >> 4) * 4;
#pragma unroll
        for (int i = 0; i < 4; i++) {
            int r = r0 + i;
            float4 v = *(const float4*)&src[(size_t)(y0 + r) * Dz + x0 + c4];
            t[r][c4 + 0] = f2bf(v.x); t[r][c4 + 1] = f2bf(v.y);
            t[r][c4 + 2] = f2bf(v.z); t[r][c4 + 3] = f2bf(v.w);
        }
    }
    __syncthreads();
    // store: 2 consecutive dst cols (one u32) x 8 dst rows per thread
    {
        int ce = (threadIdx.x & 31) * 2, r0 = (threadIdx.x >> 5) * 8;
#pragma unroll
        for (int j = 0; j < 8; j++) {
            int r = r0 + j;                            // dst row = source col
            u32 w = (u32)t[ce][r] | ((u32)t[ce + 1][r] << 16);
            *(u32*)&dst[(size_t)(x0 + r) * Dz + y0 + ce] = w;
        }
    }
}

// ---------------- GEMM: C = A[M,K](bf16) * Wt[N,K]^T(bf16), 128x128 tile ----
// global_load_lds staging + XOR-swizzled LDS (block cb of row r stored at
// cb ^ (r&7)) -> conflict-free ds_read_b128 fragment reads.
// MODE 0: fp32 row-major store. MODE 1: bf16 scatter (z=0/1 [B,H,S,HD] with
// FUSED RoPE applied to the fp32 accumulator via native v_sin/v_cos;
// z=2 [B,H,HD,S], no RoPE).
// XCD-aware block swizzle (T1): 512-block (x,y) plane, 512 % 8 == 0 ->
// bijective simple form; each XCD owns 64 contiguous work ids = 4 A-panels
// (2 MB, L2-resident). Verified r4: FETCH 198->147 MB, dur neutral
// (structure-bound at ~930 TF, the m97 ceiling).
template <int MODE>
__global__ void gemm_bt(const u16* __restrict__ A, const u16* __restrict__ BtBase,
                        void* __restrict__ CBase) {
    const int z = blockIdx.z;
    const u16* Bt = BtBase + (size_t)z * (Dz * Dz);
    const int tid = threadIdx.x, lane = tid & 63, wave = tid >> 6;
    const int ln = lane & 15, qd = lane >> 4;
    // XCD swizzle over the 512-block (x,y) plane (assumes gridDim = (16,32,z))
    const int lid = blockIdx.y * 16 + blockIdx.x;
    const int wid = (lid & 7) * 64 + (lid >> 3);
    const int m0 = (wid >> 4) * 128, n0 = (wid & 15) * 128;

    __shared__ __align__(16) u16 As[128][64];
    __shared__ __align__(16) u16 Bs[128][64];

    f32x4 acc[4][4];
#pragma unroll
    for (int i = 0; i < 4; i++)
#pragma unroll
        for (int j = 0; j < 4; j++) acc[i][j] = (f32x4){0.f, 0.f, 0.f, 0.f};

    const int wm = (wave >> 1) * 64, wn = (wave & 1) * 64;
    const int lr8 = lane >> 3;                         // row-within-8 (= row&7)
    const int bgo = (((lane & 7) ^ lr8) * 8);          // swizzled u16 col offset
    const int x7 = ln & 7;

    for (int k0 = 0; k0 < Dz; k0 += 64) {
        const u16* ga = A  + (size_t)(m0 + wave * 32 + lr8) * Dz + k0 + bgo;
        const u16* gb = Bt + (size_t)(n0 + wave * 32 + lr8) * Dz + k0 + bgo;
#pragma unroll
        for (int i = 0; i < 4; i++) {
            gl_lds16(ga + (size_t)(8 * i) * Dz, &As[wave * 32 + 8 * i][0]);
            gl_lds16(gb + (size_t)(8 * i) * Dz, &Bs[wave * 32 + 8 * i][0]);
        }
        __syncthreads();
#pragma unroll
        for (int kc = 0; kc < 2; kc++) {
            bf16x8 af[4], bff[4];
            const int cs = ((4 * kc + qd) ^ x7) * 8;   // swizzled fragment col
#pragma unroll
            for (int i = 0; i < 4; i++) {
                af[i]  = *(const bf16x8*)&As[wm + i * 16 + ln][cs];
                bff[i] = *(const bf16x8*)&Bs[wn + i * 16 + ln][cs];
            }
#pragma unroll
            for (int i = 0; i < 4; i++)
#pragma unroll
                for (int j = 0; j < 4; j++)
                    acc[i][j] = __builtin_amdgcn_mfma_f32_16x16x32_bf16(
                        af[i], bff[j], acc[i][j], 0, 0, 0);
        }
        __syncthreads();
    }

#pragma unroll
    for (int i = 0; i < 4; i++) {
#pragma unroll
        for (int j = 0; j < 4; j++) {
#pragma unroll
            for (int r = 0; r < 4; r++) {
                int row = m0 + wm + i * 16 + qd * 4 + r;
                int col = n0 + wn + j * 16 + ln;
                if (MODE == 0) {
                    ((float*)CBase)[(size_t)row * Dz + col] = acc[i][j][r];
                } else {
                    u16* C = (u16*)CBase + (size_t)z * ((size_t)Mz * Dz);
                    float v = acc[i][j][r];
                    int bb = row >> 11, ss = row & 2047;
                    int hh = col >> 7, hd = col & 127;
                    if (z == 2) {
                        C[((size_t)(bb * Hz + hh) * HDz + hd) * Sz + ss] = f2bf(v);
                    } else {
                        // fused RoPE: partner x[hd^1] lives in adjacent lane
                        // (col = ... + ln). rotate_half: even hd -> -x[hd+1],
                        // odd hd -> +x[hd-1]. theta = ss*10000^(-(hd&63)/64);
                        // computed in REVOLUTIONS for native v_sin/v_cos:
                        // fr = 10000^(-d/64)/(2pi) = exp2(-LG*d - log2(2pi)).
                        float partner = __shfl_xor(v, 1);
                        const float LG = 0.20762050593046017f;   // log2(10000)/64
                        const float L2PI = 2.6514961294723187f;  // log2(2*pi)
                        float fr = fexp2(-LG * (float)(hd & 63) - L2PI);
                        float sn, cn;
                        sincos_rev((float)ss * fr, &sn, &cn);
                        float rot = (hd & 1) ? partner : -partner;
                        float y = v * cn + rot * sn;
                        // 1/sqrt(HD)*log2(e) folded into Q (exp2-domain flash)
                        if (z == 0) y *= 0.12751771218027603f;
                        C[((size_t)(bb * Hz + hh) * Sz + ss) * HDz + hd] = f2bf(y);
                    }
                }
            }
        }
    }
}

// ---------------- causal flash attention, S^T formulation ------------------
// Q,K: [B,H,S,HD] (Q pre-scaled, RoPE fused upstream); Vt: [B,H,HD,S];
// O: [B,S,H*HD]. Block: 4 waves x 16 q-cols = 64 q; k-tiles of 64 keys.
// S^T = K*Q^T; O^T = V^T*P^T. XOR-swizzled Ks/Vs.
// r10: (a) l computed in-register from the SAME bf16-truncated P values the
// PV MFMA consumes (replaces the ones-row of V: PV 9->8 MFMA rows, Vs
// 144->128 rows, no init loop; truncation bias still cancels exactly);
// (b) defer-max rescale (T13, THR=8 in exp2 domain): skip the O/l rescale
// unless tile max exceeds m_run+8; P bounded by 2^8, fp32 accum absorbs it.
// Load-balanced qt map: co-resident blocks {bid, bid+256, +512, +768} get
// qt = {m, 31-m, 8+m, 23-m} (bijective over 0..31): per-CU key-sum constant
// 66 tiles. bh = bid&31 -> per-XCD K/V L2 locality preserved.
__global__ __launch_bounds__(256, 4)
void flash_attn(const u16* __restrict__ Q, const u16* __restrict__ Kk,
                const u16* __restrict__ Vt, u16* __restrict__ O) {
    const int tid = threadIdx.x, lane = tid & 63, wave = tid >> 6;
    const int ln = lane & 15, qd = lane >> 4;
    const int bh = blockIdx.x & 31;
    const int g = blockIdx.x >> 5;                     // 0..31
    const int gm = g & 7, gj = g >> 3;
    const int qt = (gj == 0) ? gm : (gj == 1) ? 31 - gm
                 : (gj == 2) ? 8 + gm : 23 - gm;
    const int b = bh >> 4, h = bh & 15;
    const int q0 = qt * 64;
    const u16* Qh = Q  + (size_t)bh * Sz * HDz;
    const u16* Kh = Kk + (size_t)bh * Sz * HDz;
    const u16* Vh = Vt + (size_t)bh * HDz * Sz;

    __shared__ __align__(16) u16 Ks[64][128];          // [key][d], swizzled blocks
    __shared__ __align__(16) u16 Vs[128][64];          // [d][key], swizzled

    // Q B-fragments, direct from global (q = ln column, k = qd*8 + j)
    const int qabs = q0 + wave * 16 + ln;
    bf16x8 qf[4];
#pragma unroll
    for (int kc = 0; kc < 4; kc++) {
        uint4 t = *(const uint4*)(Qh + (size_t)qabs * HDz + kc * 32 + qd * 8);
        qf[kc] = *(const bf16x8*)&t;
    }

    float m_run = -INFINITY;
    float l_run = 0.f;                                 // per-lane l for q=ln
    f32x4 oa[8];                                       // O^T[d][q=ln]
#pragma unroll
    for (int n = 0; n < 8; n++) oa[n] = (f32x4){0.f, 0.f, 0.f, 0.f};

    const int x7 = ln & 7;
    const int l4 = lane >> 4, c16 = lane & 15;         // K staging map
    const int lr8 = lane >> 3;                         // V staging map
    const int bgv = ((lane & 7) ^ lr8) * 8;

    for (int k0 = 0; k0 <= q0; k0 += 64) {
        // async stage K (64x128) and V (128x64), swizzled
        {
#pragma unroll
            for (int i = 0; i < 4; i++) {
                int rw = 4 * (i & 1) + l4;             // (row & 7)
                const u16* gk = Kh + (size_t)(k0 + 16 * wave + 4 * i + l4) * HDz
                                   + ((c16 ^ rw) * 8);
                gl_lds16(gk, &Ks[16 * wave + 4 * i][0]);
            }
            const u16* gv = Vh + (size_t)(32 * wave + lr8) * Sz + k0 + bgv;
#pragma unroll
            for (int i = 0; i < 4; i++)
                gl_lds16(gv + (size_t)(8 * i) * Sz, &Vs[32 * wave + 8 * i][0]);
        }
        __syncthreads();

        // S^T tile: C[key=mt*16+qd*4+r][q=ln]
        f32x4 sc4[4];
#pragma unroll
        for (int mt = 0; mt < 4; mt++) sc4[mt] = (f32x4){0.f, 0.f, 0.f, 0.f};
#pragma unroll
        for (int kc = 0; kc < 4; kc++) {
            const int cs = ((4 * kc + qd) ^ x7) * 8;
#pragma unroll
            for (int mt = 0; mt < 4; mt++) {
                bf16x8 kf = *(const bf16x8*)&Ks[mt * 16 + ln][cs];
                sc4[mt] = __builtin_amdgcn_mfma_f32_16x16x32_bf16(kf, qf[kc], sc4[mt], 0, 0, 0);
            }
        }
        if (k0 == q0) {                                // causal mask, diagonal tile only
#pragma unroll
            for (int mt = 0; mt < 4; mt++)
#pragma unroll
                for (int r = 0; r < 4; r++)
                    if (mt * 16 + qd * 4 + r > 16 * wave + ln) sc4[mt][r] = -3e38f;
        }

        // row max: in-register + cross-quad (rm = max over tile keys, q=ln)
        float rm = -3e38f;
#pragma unroll
        for (int mt = 0; mt < 4; mt++) {
            rm = fmaxf(rm, fmaxf(fmaxf(sc4[mt][0], sc4[mt][1]),
                                 fmaxf(sc4[mt][2], sc4[mt][3])));
        }
        rm = fmaxf(rm, __shfl_xor(rm, 16));
        rm = fmaxf(rm, __shfl_xor(rm, 32));
        // defer-max: only rescale when the tile max exceeds m_run by > 8
        if (__ballot(rm > m_run + 8.f) != 0ULL) {
            float mn = fmaxf(m_run, rm);
            float al = fexp2(m_run - mn);
            m_run = mn;
            l_run *= al;
#pragma unroll
            for (int n = 0; n < 8; n++)
#pragma unroll
                for (int r = 0; r < 4; r++) oa[n][r] *= al;
        }

        // P = exp2(S - m) <= 2^8, packed bf16 pairs; l summed from the
        // TRUNCATED values (bit-consistent with what PV consumes)
        u32 pku[8];
        float ls = 0.f;
#pragma unroll
        for (int mt = 0; mt < 4; mt++) {
#pragma unroll
            for (int t = 0; t < 2; t++) {
                u32 w = pack_bf16_trunc(fexp2(sc4[mt][2 * t] - m_run),
                                        fexp2(sc4[mt][2 * t + 1] - m_run));
                pku[mt * 2 + t] = w;
                union { u32 u; float f; } t0, t1;
                t0.u = w << 16; t1.u = w & 0xFFFF0000u;
                ls += t0.f + t1.f;
            }
        }
        ls += __shfl_xor(ls, 16);
        ls += __shfl_xor(ls, 32);
        l_run += ls;

        // O^T += V^T * P^T  (B-frag of P^T built by register shuffle)
#pragma unroll
        for (int kc = 0; kc < 2; kc++) {
            union { u32 w[4]; bf16x8 v; } pb;
#pragma unroll
            for (int s = 0; s < 4; s++) {
                int srcl = ((2 * (qd & 1) + (s >> 1)) << 4) | ln;
                u32 a0 = (u32)__shfl((int)pku[4 * kc + (s & 1)], srcl);
                u32 a1 = (u32)__shfl((int)pku[4 * kc + 2 + (s & 1)], srcl);
                pb.w[s] = (qd & 2) ? a1 : a0;
            }
            const int cs = ((4 * kc + qd) ^ x7) * 8;
#pragma unroll
            for (int mt = 0; mt < 8; mt++) {
                bf16x8 vf = *(const bf16x8*)&Vs[mt * 16 + ln][cs];
                oa[mt] = __builtin_amdgcn_mfma_f32_16x16x32_bf16(vf, pb.v, oa[mt], 0, 0, 0);
            }
        }
        __syncthreads();
    }

    // normalize and store O[q][d]; every lane holds l for its own q=ln
    float linv = 1.0f / l_run;
    u16* op = O + ((size_t)b * Sz + qabs) * Dz + h * HDz;
#pragma unroll
    for (int mt = 0; mt < 8; mt++) {
        u32 w0 = pack_bf16_rn(oa[mt][0] * linv, oa[mt][1] * linv);
        u32 w1 = pack_bf16_rn(oa[mt][2] * linv, oa[mt][3] * linv);
        uint2 ww; ww.x = w0; ww.y = w1;
        *(uint2*)(op + mt * 16 + qd * 4) = ww;
    }
}

// ---------------------------------------------------------------------------
extern "C" void kernel_launch(void* const* d_in, const int* in_sizes, int n_in,
                              void* d_out, int out_size, void* d_ws, size_t ws_size,
                              hipStream_t stream) {
    const float* x  = (const float*)d_in[0];
    const float* Wq = (const float*)d_in[1];
    const float* Wk = (const float*)d_in[2];
    const float* Wv = (const float*)d_in[3];
    const float* Wo = (const float*)d_in[4];
    u16* ws  = (u16*)d_ws;

    u16* wt = ws;                       // 4 * 4,194,304 transposed bf16 weights (32 MB)
    u16* q  = ws + 16777216;            // [B,H,S,HD] (RoPE+scale fused in gemm)
    u16* kk = q + 8388608;              // [B,H,S,HD] (RoPE fused in gemm)
    u16* v  = kk + 8388608;             // [B,H,HD,S]
    u16* xb = v + 8388608;              // bf16(x); reused as o after gemm<1>
    u16* o  = xb;

    prep<<<dim3(32, 32, 8), 256, 0, stream>>>(x, Wq, Wk, Wv, Wo, wt, xb);
    gemm_bt<1><<<dim3(16, 32, 3), 256, 0, stream>>>(xb, wt, q);
    flash_attn<<<dim3(1024), 256, 0, stream>>>(q, kk, v, o);
    gemm_bt<0><<<dim3(16, 32, 1), 256, 0, stream>>>(o, wt + 3 * 4194304, (float*)d_out);
}